// Round 1
// 191.790 us; speedup vs baseline: 1.0412x; 1.0412x over previous
//
#include <hip/hip_runtime.h>

// MeanEmbedding: out[b,d] = (1/len[b]) * sum_{s<len[b]} xs[b,s,d]
// xs: [B=16, S=4096, D=512] fp32, xs_len: [B] int32, out: [B, D] fp32.
//
// Two-stage, atomic-free reduction:
//  Stage 1: grid (B, S/16). Each block sums a 16-row slab across the full
//           D width (128 lanes x float4, coalesced, 16 independent loads in
//           flight) and writes a 2 KB partial to d_ws. Blocks past len[b]
//           exit immediately; ~2048 blocks active on average (~8 waves/CU)
//           vs ~512 before -> enough TLP to hide HBM latency.
//  Stage 2: grid (B, 4), 128 threads. Each block reduces 32 float4 columns
//           over the ceil(len/16) valid partials (4 chunk-lanes per column,
//           LDS combine), scales by 1/len, writes out directly.
// No atomics, no output memset (stage 2 writes every element).

#define ROWS   16         // rows per stage-1 slab
#define T1     128        // D/4 = 512/4 float4 lanes per row
#define T2     128

__global__ __launch_bounds__(T1) void mean_embed_stage1(
    const float4* __restrict__ xs,
    const int*    __restrict__ xs_len,
    float4*       __restrict__ ws,
    int S, int nchunks)
{
    const int b     = blockIdx.x;
    const int chunk = blockIdx.y;
    const int L     = xs_len[b];
    const int row0  = chunk * ROWS;
    if (row0 >= L) return;                    // slab entirely masked out
    const int row1 = min(row0 + ROWS, L);
    const int tid  = threadIdx.x;             // float4 column 0..127

    const float4* base = xs + (size_t)b * S * T1;

    float4 acc = make_float4(0.f, 0.f, 0.f, 0.f);
    if (row1 - row0 == ROWS) {
        // full slab: 16 independent loads, fully unrolled
        #pragma unroll
        for (int i = 0; i < ROWS; ++i) {
            float4 v = base[(size_t)(row0 + i) * T1 + tid];
            acc.x += v.x; acc.y += v.y; acc.z += v.z; acc.w += v.w;
        }
    } else {
        for (int s = row0; s < row1; ++s) {
            float4 v = base[(size_t)s * T1 + tid];
            acc.x += v.x; acc.y += v.y; acc.z += v.z; acc.w += v.w;
        }
    }

    ws[((size_t)b * nchunks + chunk) * T1 + tid] = acc;
}

__global__ __launch_bounds__(T2) void mean_embed_stage2(
    const float4* __restrict__ ws,
    const int*    __restrict__ xs_len,
    float4*       __restrict__ out,
    int nchunks)
{
    const int b   = blockIdx.x;
    const int tid = threadIdx.x;
    const int col = blockIdx.y * 32 + (tid & 31); // float4 column 0..127
    const int cl  = tid >> 5;                     // chunk lane 0..3
    const int L   = xs_len[b];
    const int nch = (L + ROWS - 1) / ROWS;        // valid partial count

    float4 acc = make_float4(0.f, 0.f, 0.f, 0.f);
    for (int c = cl; c < nch; c += 4) {
        float4 v = ws[((size_t)b * nchunks + c) * T1 + col];
        acc.x += v.x; acc.y += v.y; acc.z += v.z; acc.w += v.w;
    }

    __shared__ float4 red[T2];
    red[tid] = acc;
    __syncthreads();

    if (tid < 32) {
        float4 a0 = red[tid];
        float4 a1 = red[tid + 32];
        float4 a2 = red[tid + 64];
        float4 a3 = red[tid + 96];
        const float inv = 1.0f / (float)L;
        float4 r;
        r.x = (a0.x + a1.x + a2.x + a3.x) * inv;
        r.y = (a0.y + a1.y + a2.y + a3.y) * inv;
        r.z = (a0.z + a1.z + a2.z + a3.z) * inv;
        r.w = (a0.w + a1.w + a2.w + a3.w) * inv;
        out[(size_t)b * T1 + col] = r;            // col == blockIdx.y*32 + tid
    }
}

extern "C" void kernel_launch(void* const* d_in, const int* in_sizes, int n_in,
                              void* d_out, int out_size, void* d_ws, size_t ws_size,
                              hipStream_t stream) {
    const float4* xs     = (const float4*)d_in[0];
    const int*    xs_len = (const int*)d_in[1];
    float4*       out    = (float4*)d_out;
    float4*       ws     = (float4*)d_ws;

    const int B = in_sizes[1];                 // 16
    const int total = in_sizes[0];             // B*S*D
    const int D = 512;
    const int S = total / (B * D);             // 4096
    const int nchunks = (S + ROWS - 1) / ROWS; // 256

    // ws usage: B * nchunks * 128 float4 = 8 MB (<< ws_size)
    dim3 g1(B, nchunks);
    mean_embed_stage1<<<g1, T1, 0, stream>>>(xs, xs_len, ws, S, nchunks);

    dim3 g2(B, 4);
    mean_embed_stage2<<<g2, T2, 0, stream>>>(ws, xs_len, out, nchunks);
}